// Round 2
// baseline (804.416 us; speedup 1.0000x reference)
//
#include <hip/hip_runtime.h>
#include <hip/hip_bf16.h>

typedef _Float16 h16;
typedef __attribute__((ext_vector_type(8))) _Float16 halfx8;
typedef __attribute__((ext_vector_type(4))) _Float16 halfx4;
typedef __attribute__((ext_vector_type(4))) float f32x4;

__device__ __forceinline__ void gload_lds16(const void* g, void* l) {
  __builtin_amdgcn_global_load_lds((const __attribute__((address_space(1))) unsigned int*)g,
                                   (__attribute__((address_space(3))) unsigned int*)l, 16, 0, 0);
}
__device__ __forceinline__ unsigned umax_(unsigned a, unsigned b) { return a > b ? a : b; }
__device__ __forceinline__ unsigned umin_(unsigned a, unsigned b) { return a < b ? a : b; }

// tanh-form GELU via sigmoid: x*sigmoid(1.5957691x + 0.0713548x^3)
__device__ __forceinline__ float fast_gelu(float v) {
  float x2 = v * v;
  float w_ = v * fmaf(x2, 0.0713548163f, 1.5957691216f);
  float e = __expf(w_);
  float r = 1.f / (1.f + e);
  return v * e * r;
}

// ---------------- all weight transposes + fp16 cast in one kernel ----------------
__global__ __launch_bounds__(256) void conv_all_kernel(
    const float* __restrict__ qw, const float* __restrict__ ow,
    const float* __restrict__ f1w, const float* __restrict__ f2w,
    h16* __restrict__ qwT, h16* __restrict__ owT,
    h16* __restrict__ f1T, h16* __restrict__ f2T)
{
  int bid = blockIdx.x, tid = threadIdx.x;
  const float* in; h16* out; int logN, K, base;
  if (bid < 256)       { in = qw;  out = qwT; logN = 8;  K = 256;  base = 0; }
  else if (bid < 512)  { in = ow;  out = owT; logN = 8;  K = 256;  base = 256; }
  else if (bid < 1536) { in = f1w; out = f1T; logN = 10; K = 256;  base = 512; }
  else                 { in = f2w; out = f2T; logN = 8;  K = 1024; base = 1536; }
  int idx = (bid - base) * 256 + tid;
  int k = idx >> logN, n = idx & ((1 << logN) - 1);
  out[(size_t)n * K + k] = (h16)in[idx];
}

// ---------------- text K/V: proj + bias, l2norm(k)*scale, pad mask ----------------
__global__ __launch_bounds__(256) void text_kv_kernel(const float* __restrict__ tf,
    const float* __restrict__ kw, const float* __restrict__ kb,
    const float* __restrict__ vw, const float* __restrict__ vb,
    const float* __restrict__ lsp,
    h16* __restrict__ ko, h16* __restrict__ vo, float* __restrict__ padf)
{
  __shared__ h16 st[4 * 512];
  __shared__ float kro[4 * 256];
  __shared__ float ssc[4];
  int bx = blockIdx.x, b = bx / 20, tg = bx % 20, t0 = tg * 4;
  int tid = threadIdx.x, lane = tid & 63, wid = tid >> 6;
  for (int i = tid; i < 4 * 512; i += 256) {
    int tl = i >> 9, j = i & 511, t = t0 + tl;
    float v = (t < 77) ? tf[((size_t)b * 77 + t) * 512 + j] : 0.f;
    st[i] = (h16)v;
  }
  __syncthreads();
  {
    int t = t0 + wid;
    float a = 0.f;
    #pragma unroll
    for (int j = 0; j < 8; j++) a += fabsf((float)st[wid * 512 + lane + j * 64]);
    #pragma unroll
    for (int o = 32; o; o >>= 1) a += __shfl_xor(a, o);
    if (lane == 0) padf[b * 80 + t] = (a <= 1e-6f) ? -1e30f : 0.f;
  }
  int c = tid;
  float kacc[4], vacc[4];
  #pragma unroll
  for (int tl = 0; tl < 4; tl++) { kacc[tl] = kb[c]; vacc[tl] = vb[c]; }
  for (int j = 0; j < 512; j++) {
    float wkv = kw[(size_t)j * 256 + c];
    float wvv = vw[(size_t)j * 256 + c];
    #pragma unroll
    for (int tl = 0; tl < 4; tl++) {
      float x = (float)st[tl * 512 + j];
      kacc[tl] += x * wkv; vacc[tl] += x * wvv;
    }
  }
  #pragma unroll
  for (int tl = 0; tl < 4; tl++) kro[tl * 256 + c] = kacc[tl] * kacc[tl];
  __syncthreads();
  {
    float s2 = kro[wid * 256 + lane] + kro[wid * 256 + lane + 64]
             + kro[wid * 256 + lane + 128] + kro[wid * 256 + lane + 192];
    #pragma unroll
    for (int o = 32; o; o >>= 1) s2 += __shfl_xor(s2, o);
    if (lane == 0) {
      float ls = lsp[0];
      float scale = __expf(fminf(fmaxf(ls, -2.f), 2.f)) * rsqrtf(32.f);
      ssc[wid] = scale / fmaxf(sqrtf(s2), 1e-6f);
    }
  }
  __syncthreads();
  int h = c >> 5, d = c & 31, g = d >> 3, e = d & 7;
  #pragma unroll
  for (int tl = 0; tl < 4; tl++) {
    int t = t0 + tl;
    int kt = t >> 4, l15 = t & 15, ln = g * 16 + l15;
    size_t koff = ((((size_t)(b * 8 + h) * 5 + kt) * 64) + ln) * 8 + e;
    size_t voff = (((size_t)(b * 8 + h) * 80) + t) * 32 + d;
    ko[koff] = (t < 77) ? (h16)(kacc[tl] * ssc[tl]) : (h16)0.f;
    vo[voff] = (t < 77) ? (h16)vacc[tl] : (h16)0.f;
  }
}

// ---------------- LN1 + gate + fp16 x ----------------
__global__ __launch_bounds__(256) void ln1_kernel(const float* __restrict__ vis,
    const float* __restrict__ w, const float* __restrict__ bia,
    const float* __restrict__ gw, const float* __restrict__ gb,
    h16* __restrict__ x, float* __restrict__ gate)
{
  int lane = threadIdx.x & 63;
  size_t row = (size_t)blockIdx.x * 4 + (threadIdx.x >> 6);
  const float4 v = ((const float4*)(vis + row * 256))[lane];
  float s = v.x + v.y + v.z + v.w;
  float q = v.x * v.x + v.y * v.y + v.z * v.z + v.w * v.w;
  #pragma unroll
  for (int o = 32; o; o >>= 1) { s += __shfl_xor(s, o); q += __shfl_xor(q, o); }
  float mean = s * (1.f / 256.f);
  float rstd = rsqrtf(q * (1.f / 256.f) - mean * mean + 1e-5f);
  float4 wv = ((const float4*)w)[lane], bv = ((const float4*)bia)[lane];
  float x0 = (v.x - mean) * rstd * wv.x + bv.x;
  float x1 = (v.y - mean) * rstd * wv.y + bv.y;
  float x2 = (v.z - mean) * rstd * wv.z + bv.z;
  float x3 = (v.w - mean) * rstd * wv.w + bv.w;
  float4 gv = ((const float4*)gw)[lane];
  float g = x0 * gv.x + x1 * gv.y + x2 * gv.z + x3 * gv.w;
  #pragma unroll
  for (int o = 32; o; o >>= 1) g += __shfl_xor(g, o);
  if (lane == 0) gate[row] = 1.f / (1.f + __expf(-(g + gb[0])));
  halfx4 o4; o4[0] = (h16)x0; o4[1] = (h16)x1; o4[2] = (h16)x2; o4[3] = (h16)x3;
  ((halfx4*)(x + row * 256))[lane] = o4;
}

// ---------------- gemmQ: q = l2norm(x @ qwT^T + qb), tile 64x256, T2-swizzled LDS ----------------
__global__ __launch_bounds__(256) void gemmQ_kernel(const h16* __restrict__ A,
    const h16* __restrict__ Wt, const float* __restrict__ bias, h16* __restrict__ outp)
{
  __shared__ char sA[8192];
  __shared__ char sB[32768];
  int m0 = blockIdx.x * 64;
  int tid = threadIdx.x, lane = tid & 63, wid = tid >> 6;
  int wn = wid;
  int l15 = lane & 15, l4 = lane >> 4, xk = l15 & 7;
  f32x4 acc[4][4];
  #pragma unroll
  for (int a = 0; a < 4; a++)
    #pragma unroll
    for (int b2 = 0; b2 < 4; b2++) acc[a][b2] = (f32x4){0.f, 0.f, 0.f, 0.f};
  const size_t sa = 512;
  int srow = lane >> 3;
  int scol = ((lane & 7) ^ srow) * 16;
  const char* Ab = (const char*)A + (size_t)m0 * sa + scol;
  const char* Bb = (const char*)Wt + scol;
  for (int k0 = 0; k0 < 256; k0 += 64) {
    #pragma unroll
    for (int cc = 0; cc < 2; cc++) {
      int ch = wid * 2 + cc;
      gload_lds16(Ab + (size_t)(ch * 8 + srow) * sa + k0 * 2, sA + ch * 1024);
    }
    #pragma unroll
    for (int cc = 0; cc < 8; cc++) {
      int ch = wid * 8 + cc;
      gload_lds16(Bb + (size_t)(ch * 8 + srow) * sa + k0 * 2, sB + ch * 1024);
    }
    asm volatile("s_waitcnt vmcnt(0)" ::: "memory");
    __syncthreads();
    #pragma unroll
    for (int ks = 0; ks < 2; ks++) {
      halfx8 af[4], bf[4];
      #pragma unroll
      for (int f = 0; f < 4; f++) {
        af[f] = *(const halfx8*)(sA + (f * 16 + l15) * 128 + (((ks * 4 + l4) ^ xk) * 16));
        bf[f] = *(const halfx8*)(sB + (wn * 64 + f * 16 + l15) * 128 + (((ks * 4 + l4) ^ xk) * 16));
      }
      #pragma unroll
      for (int fm = 0; fm < 4; fm++)
        #pragma unroll
        for (int fn = 0; fn < 4; fn++)
          acc[fm][fn] = __builtin_amdgcn_mfma_f32_16x16x32_f16(af[fm], bf[fn], acc[fm][fn], 0, 0, 0);
    }
    __syncthreads();
  }
  float bv[4];
  #pragma unroll
  for (int fn = 0; fn < 4; fn++) bv[fn] = bias[wn * 64 + fn * 16 + l15];
  float ps[4][4];
  #pragma unroll
  for (int fm = 0; fm < 4; fm++)
    #pragma unroll
    for (int r = 0; r < 4; r++) {
      float s = 0.f;
      #pragma unroll
      for (int fn = 0; fn < 4; fn++) {
        float v = acc[fm][fn][r] + bv[fn];
        acc[fm][fn][r] = v;
        s += v * v;
      }
      ps[fm][r] = s;
    }
  #pragma unroll
  for (int o = 1; o <= 8; o <<= 1)
    #pragma unroll
    for (int fm = 0; fm < 4; fm++)
      #pragma unroll
      for (int r = 0; r < 4; r++) ps[fm][r] += __shfl_xor(ps[fm][r], o);
  if (l15 == 0) {
    #pragma unroll
    for (int fm = 0; fm < 4; fm++)
      #pragma unroll
      for (int r = 0; r < 4; r++)
        ((float*)sA)[(fm * 16 + l4 * 4 + r) * 4 + wn] = ps[fm][r];
  }
  __syncthreads();
  #pragma unroll
  for (int fm = 0; fm < 4; fm++)
    #pragma unroll
    for (int r = 0; r < 4; r++) {
      const float* p = (const float*)sA + (fm * 16 + l4 * 4 + r) * 4;
      float S = p[0] + p[1] + p[2] + p[3];
      float sc = 1.f / fmaxf(sqrtf(S), 1e-6f);
      size_t row = (size_t)(m0 + fm * 16 + l4 * 4 + r);
      #pragma unroll
      for (int fn = 0; fn < 4; fn++)
        outp[row * 256 + wn * 64 + fn * 16 + l15] = (h16)(acc[fm][fn][r] * sc);
    }
}

// ---------------- gemmO: y2 = LN2(x + alpha*gate*(aligned @ owT^T + ob)), T2-swizzled ----------------
__global__ __launch_bounds__(256) void gemmO_kernel(const h16* __restrict__ A,
    const h16* __restrict__ Wt, const float* __restrict__ ob,
    const h16* __restrict__ x, const float* __restrict__ gate,
    const float* __restrict__ alphap, const float* __restrict__ w2,
    const float* __restrict__ b2, h16* __restrict__ outp)
{
  __shared__ char sA[8192];
  __shared__ char sB[32768];
  int m0 = blockIdx.x * 64;
  int tid = threadIdx.x, lane = tid & 63, wid = tid >> 6;
  int wn = wid;
  int l15 = lane & 15, l4 = lane >> 4, xk = l15 & 7;
  f32x4 acc[4][4];
  #pragma unroll
  for (int a = 0; a < 4; a++)
    #pragma unroll
    for (int b2_ = 0; b2_ < 4; b2_++) acc[a][b2_] = (f32x4){0.f, 0.f, 0.f, 0.f};
  const size_t sa = 512;
  int srow = lane >> 3;
  int scol = ((lane & 7) ^ srow) * 16;
  const char* Ab = (const char*)A + (size_t)m0 * sa + scol;
  const char* Bb = (const char*)Wt + scol;
  for (int k0 = 0; k0 < 256; k0 += 64) {
    #pragma unroll
    for (int cc = 0; cc < 2; cc++) {
      int ch = wid * 2 + cc;
      gload_lds16(Ab + (size_t)(ch * 8 + srow) * sa + k0 * 2, sA + ch * 1024);
    }
    #pragma unroll
    for (int cc = 0; cc < 8; cc++) {
      int ch = wid * 8 + cc;
      gload_lds16(Bb + (size_t)(ch * 8 + srow) * sa + k0 * 2, sB + ch * 1024);
    }
    asm volatile("s_waitcnt vmcnt(0)" ::: "memory");
    __syncthreads();
    #pragma unroll
    for (int ks = 0; ks < 2; ks++) {
      halfx8 af[4], bf[4];
      #pragma unroll
      for (int f = 0; f < 4; f++) {
        af[f] = *(const halfx8*)(sA + (f * 16 + l15) * 128 + (((ks * 4 + l4) ^ xk) * 16));
        bf[f] = *(const halfx8*)(sB + (wn * 64 + f * 16 + l15) * 128 + (((ks * 4 + l4) ^ xk) * 16));
      }
      #pragma unroll
      for (int fm = 0; fm < 4; fm++)
        #pragma unroll
        for (int fn = 0; fn < 4; fn++)
          acc[fm][fn] = __builtin_amdgcn_mfma_f32_16x16x32_f16(af[fm], bf[fn], acc[fm][fn], 0, 0, 0);
    }
    __syncthreads();
  }
  float bv[4], w2v[4], b2v[4];
  #pragma unroll
  for (int fn = 0; fn < 4; fn++) {
    int col = wn * 64 + fn * 16 + l15;
    bv[fn] = ob[col]; w2v[fn] = w2[col]; b2v[fn] = b2[col];
  }
  float al = alphap[0];
  float s1[4][4], s2[4][4];
  #pragma unroll
  for (int fm = 0; fm < 4; fm++)
    #pragma unroll
    for (int r = 0; r < 4; r++) {
      size_t row = (size_t)(m0 + fm * 16 + l4 * 4 + r);
      float ga = al * gate[row];
      float a1 = 0.f, a2 = 0.f;
      #pragma unroll
      for (int fn = 0; fn < 4; fn++) {
        float v = acc[fm][fn][r] + bv[fn];
        float xv = (float)x[row * 256 + wn * 64 + fn * 16 + l15];
        float y = xv + ga * v;
        acc[fm][fn][r] = y;
        a1 += y; a2 += y * y;
      }
      s1[fm][r] = a1; s2[fm][r] = a2;
    }
  #pragma unroll
  for (int o = 1; o <= 8; o <<= 1)
    #pragma unroll
    for (int fm = 0; fm < 4; fm++)
      #pragma unroll
      for (int r = 0; r < 4; r++) {
        s1[fm][r] += __shfl_xor(s1[fm][r], o);
        s2[fm][r] += __shfl_xor(s2[fm][r], o);
      }
  if (l15 == 0) {
    #pragma unroll
    for (int fm = 0; fm < 4; fm++)
      #pragma unroll
      for (int r = 0; r < 4; r++) {
        int rr = fm * 16 + l4 * 4 + r;
        ((float*)sA)[rr * 8 + wn * 2 + 0] = s1[fm][r];
        ((float*)sA)[rr * 8 + wn * 2 + 1] = s2[fm][r];
      }
  }
  __syncthreads();
  #pragma unroll
  for (int fm = 0; fm < 4; fm++)
    #pragma unroll
    for (int r = 0; r < 4; r++) {
      int rr = fm * 16 + l4 * 4 + r;
      const float* p = (const float*)sA + rr * 8;
      float S1 = p[0] + p[2] + p[4] + p[6];
      float S2 = p[1] + p[3] + p[5] + p[7];
      float mean = S1 * (1.f / 256.f);
      float var = S2 * (1.f / 256.f) - mean * mean;
      float rstd = rsqrtf(var + 1e-5f);
      size_t row = (size_t)(m0 + rr);
      #pragma unroll
      for (int fn = 0; fn < 4; fn++) {
        float y = acc[fm][fn][r];
        outp[row * 256 + wn * 64 + fn * 16 + l15] =
            (h16)((y - mean) * rstd * w2v[fn] + b2v[fn]);
      }
    }
}

// ---------------- fused FFN v3: chunk=32, 76KB LDS -> 2 blocks/CU (cross-block overlap) ----
// 512 threads = 8 waves. Block owns 128 rows. 32 hidden chunks of 32.
// Double-buffered weight staging, counted vmcnt(4). 3 raw barriers/chunk; the
// serialization of one block's phases is hidden by the co-resident block.
// sH swizzle XORs granule with (row>>2)&3 (varies with l4) -> conflict-free writes.
__device__ __forceinline__ void ffn_stage(const h16* __restrict__ w1t,
                                          const h16* __restrict__ w2t,
                                          int c, char* dW1, char* dW2, int tid, int wid)
{
  #pragma unroll
  for (int j = 0; j < 2; j++) {
    int i = j * 512 + tid;
    int r = i >> 5, g = i & 31;                  // [32 n1][32 granules of 16B]
    gload_lds16(w1t + (size_t)(c * 32 + r) * 256 + ((g ^ (r & 7)) * 8),
                dW1 + (j * 512 + wid * 64) * 16);
  }
  #pragma unroll
  for (int j = 0; j < 2; j++) {
    int i = j * 512 + tid;
    int r = i >> 2, g = i & 3;                   // [256 n][4 granules of 16B]
    gload_lds16(w2t + (size_t)r * 1024 + c * 32 + ((g ^ (r & 3)) * 8),
                dW2 + (j * 512 + wid * 64) * 16);
  }
}

__global__ __launch_bounds__(512, 4) void ffn_fused_kernel(
    const h16* __restrict__ y2g, const h16* __restrict__ w1t, const float* __restrict__ b1,
    const h16* __restrict__ w2t, const float* __restrict__ b2, float* __restrict__ outp)
{
  // [0,32768)       sW1 double buffer (2 x 16384)  [32 n1][256 k] h16 swizzled
  // [32768,65536)   sW2 double buffer (2 x 16384)  [256 n][32 k] h16 swizzled
  // [65536,73728)   sH [128][32] h16, granule ^ (row>>2)&3
  // [73728,77824)   sB1: b1 staged as f32 (keeps in-loop vmcnt exact)
  // total 77824 B -> 2 blocks/CU (155648 <= 163840)
  __shared__ char smem[77824];
  char* sH = smem + 65536;
  float* sB1 = (float*)(smem + 73728);
  float* sE = (float*)smem;     // [64][264] f32 epilogue (aliases weights+sH head)

  int m0 = blockIdx.x * 128;
  int tid = threadIdx.x, lane = tid & 63, wid = tid >> 6;
  int l15 = lane & 15, l4 = lane >> 4;
  int wm1 = wid >> 1, wn1 = wid & 1;
  int wm2 = wid >> 2, wn2 = wid & 3;

  // b1 -> LDS (1024 f32; 512 threads x 8B)
  ((float2*)sB1)[tid] = ((const float2*)b1)[tid];

  // cache y2 A-fragments in registers (reused by all 32 chunks)
  halfx8 afy[2][8];
  #pragma unroll
  for (int fm = 0; fm < 2; fm++) {
    size_t row = (size_t)(m0 + wm1 * 32 + fm * 16 + l15);
    #pragma unroll
    for (int ks = 0; ks < 8; ks++)
      afy[fm][ks] = *(const halfx8*)&y2g[row * 256 + ks * 32 + l4 * 8];
  }

  f32x4 acc2[4][4];
  #pragma unroll
  for (int a = 0; a < 4; a++)
    #pragma unroll
    for (int b_ = 0; b_ < 4; b_++) acc2[a][b_] = (f32x4){0.f, 0.f, 0.f, 0.f};

  // prologue: stage chunk 0 into buffer 0
  ffn_stage(w1t, w2t, 0, smem, smem + 32768, tid, wid);
  // drain own ds_write of sB1 before first barrier (cross-wave visibility)
  asm volatile("s_waitcnt lgkmcnt(0)" ::: "memory");

  for (int c = 0; c < 32; c++) {
    int buf = c & 1;
    char* sW1 = smem + buf * 16384;
    char* sW2 = smem + 32768 + buf * 16384;
    if (c < 31) {
      ffn_stage(w1t, w2t, c + 1, smem + (buf ^ 1) * 16384,
                smem + 32768 + (buf ^ 1) * 16384, tid, wid);
      asm volatile("s_waitcnt vmcnt(4)" ::: "memory");  // chunk-c loads landed; c+1 in flight
    } else {
      asm volatile("s_waitcnt vmcnt(0)" ::: "memory");
    }
    __builtin_amdgcn_s_barrier();
    asm volatile("" ::: "memory");

    float b1v = sB1[c * 32 + wn1 * 16 + l15];

    // gemm1: H_chunk[128][32], tile 32x16 per wave
    f32x4 a1[2];
    a1[0] = (f32x4){0.f, 0.f, 0.f, 0.f};
    a1[1] = (f32x4){0.f, 0.f, 0.f, 0.f};
    __builtin_amdgcn_s_setprio(1);
    #pragma unroll
    for (int ks = 0; ks < 8; ks++) {
      int nrow = wn1 * 16 + l15;
      halfx8 bf = *(const halfx8*)(sW1 + (size_t)nrow * 512 + (((ks * 4 + l4) ^ (nrow & 7)) * 16));
      #pragma unroll
      for (int fm = 0; fm < 2; fm++)
        a1[fm] = __builtin_amdgcn_mfma_f32_16x16x32_f16(afy[fm][ks], bf, a1[fm], 0, 0, 0);
    }
    __builtin_amdgcn_s_setprio(0);
    // gelu -> sH (granule swizzle varies with l4 -> 2-way max, free)
    #pragma unroll
    for (int fm = 0; fm < 2; fm++)
      #pragma unroll
      for (int r = 0; r < 4; r++) {
        int row = wm1 * 32 + fm * 16 + l4 * 4 + r;
        int col = wn1 * 16 + l15;
        float v = fast_gelu(a1[fm][r] + b1v);
        ((h16*)(sH + row * 64 + (((col >> 3) ^ ((row >> 2) & 3)) * 16)))[col & 7] = (h16)v;
      }
    asm volatile("s_waitcnt lgkmcnt(0)" ::: "memory");  // DS drain only — vmcnt stays in flight
    __builtin_amdgcn_s_barrier();
    asm volatile("" ::: "memory");
    // gemm2: acc2 += H @ W2  (K=32: single ks)
    __builtin_amdgcn_s_setprio(1);
    {
      halfx8 ah[4], bw[4];
      #pragma unroll
      for (int f = 0; f < 4; f++) {
        int hrow = wm2 * 64 + f * 16 + l15;
        ah[f] = *(const halfx8*)(sH + hrow * 64 + ((l4 ^ ((hrow >> 2) & 3)) * 16));
        int wrow = wn2 * 64 + f * 16 + l15;
        bw[f] = *(const halfx8*)(sW2 + (size_t)wrow * 64 + ((l4 ^ (wrow & 3)) * 16));
      }
      #pragma unroll
      for (int fm = 0; fm < 4; fm++)
        #pragma unroll
        for (int fn = 0; fn < 4; fn++)
          acc2[fm][fn] = __builtin_amdgcn_mfma_f32_16x16x32_f16(ah[fm], bw[fn], acc2[fm][fn], 0, 0, 0);
    }
    __builtin_amdgcn_s_setprio(0);
    // end-of-chunk barrier: protects sH and sW[buf^1] (next iter stages into it)
    asm volatile("" ::: "memory");
    __builtin_amdgcn_s_barrier();
    asm volatile("" ::: "memory");
  }

  // epilogue: two half-passes via padded f32 LDS; coalesced float4 stores + residual + b2
  int rowl = tid >> 3, cg = tid & 7;
  #pragma unroll
  for (int half = 0; half < 2; half++) {
    if (wm2 == half) {
      #pragma unroll
      for (int fm = 0; fm < 4; fm++)
        #pragma unroll
        for (int fn = 0; fn < 4; fn++)
          #pragma unroll
          for (int r = 0; r < 4; r++)
            sE[(fm * 16 + l4 * 4 + r) * 264 + wn2 * 64 + fn * 16 + l15] = acc2[fm][fn][r];
    }
    __syncthreads();
    size_t grow = (size_t)(m0 + half * 64 + rowl);
    #pragma unroll
    for (int k = 0; k < 8; k++) {
      int c0 = cg * 4 + k * 32;
      float4 v = *(float4*)&sE[rowl * 264 + c0];
      halfx4 rv = *(const halfx4*)&y2g[grow * 256 + c0];
      float4 bb = *(const float4*)&b2[c0];
      float4 o;
      o.x = v.x + (float)rv[0] + bb.x;
      o.y = v.y + (float)rv[1] + bb.y;
      o.z = v.z + (float)rv[2] + bb.z;
      o.w = v.w + (float)rv[3] + bb.w;
      *(float4*)&outp[grow * 256 + c0] = o;
    }
    __syncthreads();
  }
}

// ---------------- attention v6: coalesced fragment-order K, compact V ----------------
__global__ __launch_bounds__(256) void attn_kernel(const h16* __restrict__ q,
    const h16* __restrict__ kk,   // kT[b][h][kt][lane][8]
    const h16* __restrict__ vv,   // vT[b][h][80][32]
    const float* __restrict__ padf,
    h16* __restrict__ outp)       // aliases q (in-place per slice)
{
  int bx = blockIdx.x;
  int wid = threadIdx.x >> 6, lane = threadIdx.x & 63;
  int l15 = lane & 15, g = lane >> 4;
  int b = bx >> 8;
  size_t qrow = (size_t)bx * 64 + wid * 16 + l15;
  int base4 = g * 4;
  float pad4[5][4];
  #pragma unroll
  for (int kt = 0; kt < 5; kt++) {
    float4 p4 = *(const float4*)&padf[b * 80 + kt * 16 + base4];
    pad4[kt][0] = p4.x; pad4[kt][1] = p4.y; pad4[kt][2] = p4.z; pad4[kt][3] = p4.w;
  }
  const h16* qp = &q[qrow * 256 + g * 8];
  h16* op = &outp[qrow * 256 + g * 8];
  #pragma unroll 2
  for (int h = 0; h < 8; h++) {
    int ho = h * 32;
    halfx8 qf = *(const halfx8*)(qp + ho);
    const h16* kph = kk + (((size_t)(b * 8 + h) * 5) * 64 + lane) * 8;
    const h16* vph = vv + ((size_t)(b * 8 + h) * 80) * 32 + g * 8;
    f32x4 acc[5];
    #pragma unroll
    for (int kt = 0; kt < 5; kt++) {
      halfx8 kf = *(const halfx8*)(kph + kt * 512);
      acc[kt] = __builtin_amdgcn_mfma_f32_16x16x32_f16(kf, qf, (f32x4){0.f, 0.f, 0.f, 0.f}, 0, 0, 0);
    }
    unsigned pv0 = 0u, pv1 = 0u, pv2 = 0u, pv3 = 0u, pv4 = 0u;
    #pragma unroll
    for (int kt = 0; kt < 5; kt++) {
      #pragma unroll
      for (int r = 0; r < 4; r++) {
        float s = acc[kt][r] + pad4[kt][r];
        int bi = __float_as_int(s);
        unsigned u = ((unsigned)(bi ^ ((bi >> 31) | (int)0x80000000)) & 0xFFFFFF80u)
                   | (unsigned)(base4 + kt * 16 + r);
        unsigned a;
        a = umax_(pv0, u); u = umin_(pv0, u); pv0 = a;
        a = umax_(pv1, u); u = umin_(pv1, u); pv1 = a;
        a = umax_(pv2, u); u = umin_(pv2, u); pv2 = a;
        a = umax_(pv3, u); u = umin_(pv3, u); pv3 = a;
        pv4 = umax_(pv4, u);
      }
    }
    #pragma unroll
    for (int mrd = 0; mrd < 2; mrd++) {
      int msk = mrd ? 32 : 16;
      unsigned b0 = (unsigned)__shfl_xor((int)pv0, msk);
      unsigned b1 = (unsigned)__shfl_xor((int)pv1, msk);
      unsigned b2 = (unsigned)__shfl_xor((int)pv2, msk);
      unsigned b3 = (unsigned)__shfl_xor((int)pv3, msk);
      unsigned b4 = (unsigned)__shfl_xor((int)pv4, msk);
      unsigned c0 = umax_(pv0, b0);
      unsigned c1 = umax_(umax_(umin_(pv0, b0), pv1), b1);
      unsigned c2 = umax_(umax_(umin_(pv0, b1), umin_(pv1, b0)), umax_(pv2, b2));
      unsigned c3 = umax_(umax_(umax_(umin_(pv0, b2), umin_(pv1, b1)), umin_(pv2, b0)), umax_(pv3, b3));
      unsigned c4 = umax_(umax_(umax_(umin_(pv0, b3), umin_(pv1, b2)),
                                umax_(umin_(pv2, b1), umin_(pv3, b0))), umax_(pv4, b4));
      pv0 = c0; pv1 = c1; pv2 = c2; pv3 = c3; pv4 = c4;
    }
    unsigned pvs[5] = {pv0, pv1, pv2, pv3, pv4};
    float pw[5]; int ti[5]; float den = 0.f;
    #pragma unroll
    for (int k = 0; k < 5; k++) {
      unsigned u = pvs[k];
      int sg = ((int)u) >> 31;
      float tv = __int_as_float(u ^ (0x80000000u | (unsigned)~sg));
      ti[k] = (int)(u & 0x7Fu);
      pw[k] = __expf(tv);
      den += pw[k];
    }
    float inv = 1.f / den;
    halfx8 o8 = {};
    #pragma unroll
    for (int k = 0; k < 5; k++) {
      h16 ph = (h16)(pw[k] * inv);
      halfx8 v = *(const halfx8*)(vph + ti[k] * 32);
      halfx8 p8 = {ph, ph, ph, ph, ph, ph, ph, ph};
      o8 = o8 + p8 * v;
    }
    *(halfx8*)(op + ho) = o8;
  }
}

extern "C" void kernel_launch(void* const* d_in, const int* in_sizes, int n_in,
                              void* d_out, int out_size, void* d_ws, size_t ws_size,
                              hipStream_t stream)
{
  const float* vis = (const float*)d_in[0];
  const float* tf  = (const float*)d_in[1];
  const float* n1w = (const float*)d_in[2];
  const float* n1b = (const float*)d_in[3];
  const float* qw  = (const float*)d_in[4];
  const float* qb  = (const float*)d_in[5];
  const float* kw  = (const float*)d_in[6];
  const float* kb  = (const float*)d_in[7];
  const float* vw  = (const float*)d_in[8];
  const float* vb  = (const float*)d_in[9];
  const float* ow  = (const float*)d_in[10];
  const float* ob  = (const float*)d_in[11];
  const float* gw  = (const float*)d_in[12];
  const float* gb  = (const float*)d_in[13];
  const float* ls  = (const float*)d_in[14];
  const float* al  = (const float*)d_in[15];
  const float* n2w = (const float*)d_in[16];
  const float* n2b = (const float*)d_in[17];
  const float* f1w = (const float*)d_in[18];
  const float* f1b = (const float*)d_in[19];
  const float* f2w = (const float*)d_in[20];
  const float* f2b = (const float*)d_in[21];

  char* ws = (char*)d_ws;
  const size_t MB_ = 1024ull * 1024ull;
  h16*  kS   = (h16*)(ws + 0 * MB_);      // kT: 320 KB
  h16*  vS   = (h16*)(ws + 1 * MB_);      // vT: 320 KB
  float* padf = (float*)(ws + 2 * MB_);   // [8][80] f32
  float* gate = (float*)(ws + 3 * MB_);   // 512 KB
  h16*  qwT  = (h16*)(ws + 4 * MB_);      // 128 KB
  h16*  owT  = (h16*)(ws + 5 * MB_);      // 128 KB
  h16*  f1T  = (h16*)(ws + 6 * MB_);      // 512 KB
  h16*  f2T  = (h16*)(ws + 7 * MB_);      // 512 KB
  h16*  xh   = (h16*)(ws + 16 * MB_);     // 64 MB: x
  h16*  qh   = (h16*)(ws + 80 * MB_);     // 64 MB: q / attn-out in place
  h16*  alg  = (h16*)(ws + 144 * MB_);    // 64 MB: y2

  conv_all_kernel<<<2560, 256, 0, stream>>>(qw, ow, f1w, f2w, qwT, owT, f1T, f2T);

  text_kv_kernel<<<160, 256, 0, stream>>>(tf, kw, kb, vw, vb, ls, kS, vS, padf);
  ln1_kernel<<<32768, 256, 0, stream>>>(vis, n1w, n1b, gw, gb, xh, gate);

  gemmQ_kernel<<<2048, 256, 0, stream>>>(xh, qwT, qb, qh);

  attn_kernel<<<2048, 256, 0, stream>>>(qh, kS, vS, padf, qh);

  gemmO_kernel<<<2048, 256, 0, stream>>>(qh, owT, ob, xh, gate, al, n2w, n2b, alg);

  // fused FFN: d_out = alg + gelu(alg@W1+b1)@W2 + b2
  ffn_fused_kernel<<<1024, 512, 0, stream>>>(alg, f1T, f1b, f2T, f2b, (float*)d_out);
}

// Round 3
// 544.292 us; speedup vs baseline: 1.4779x; 1.4779x over previous
//
#include <hip/hip_runtime.h>
#include <hip/hip_bf16.h>

typedef _Float16 h16;
typedef __attribute__((ext_vector_type(8))) _Float16 halfx8;
typedef __attribute__((ext_vector_type(4))) _Float16 halfx4;
typedef __attribute__((ext_vector_type(4))) float f32x4;

__device__ __forceinline__ void gload_lds16(const void* g, void* l) {
  __builtin_amdgcn_global_load_lds((const __attribute__((address_space(1))) unsigned int*)g,
                                   (__attribute__((address_space(3))) unsigned int*)l, 16, 0, 0);
}
__device__ __forceinline__ unsigned umax_(unsigned a, unsigned b) { return a > b ? a : b; }
__device__ __forceinline__ unsigned umin_(unsigned a, unsigned b) { return a < b ? a : b; }

// tanh-form GELU via sigmoid: x*sigmoid(1.5957691x + 0.0713548x^3)
__device__ __forceinline__ float fast_gelu(float v) {
  float x2 = v * v;
  float w_ = v * fmaf(x2, 0.0713548163f, 1.5957691216f);
  float e = __expf(w_);
  float r = 1.f / (1.f + e);
  return v * e * r;
}

// ---------------- all weight transposes + fp16 cast in one kernel ----------------
__global__ __launch_bounds__(256) void conv_all_kernel(
    const float* __restrict__ qw, const float* __restrict__ ow,
    const float* __restrict__ f1w, const float* __restrict__ f2w,
    h16* __restrict__ qwT, h16* __restrict__ owT,
    h16* __restrict__ f1T, h16* __restrict__ f2T)
{
  int bid = blockIdx.x, tid = threadIdx.x;
  const float* in; h16* out; int logN, K, base;
  if (bid < 256)       { in = qw;  out = qwT; logN = 8;  K = 256;  base = 0; }
  else if (bid < 512)  { in = ow;  out = owT; logN = 8;  K = 256;  base = 256; }
  else if (bid < 1536) { in = f1w; out = f1T; logN = 10; K = 256;  base = 512; }
  else                 { in = f2w; out = f2T; logN = 8;  K = 1024; base = 1536; }
  int idx = (bid - base) * 256 + tid;
  int k = idx >> logN, n = idx & ((1 << logN) - 1);
  out[(size_t)n * K + k] = (h16)in[idx];
}

// ---------------- text K/V: proj + bias, l2norm(k)*scale, pad mask ----------------
__global__ __launch_bounds__(256) void text_kv_kernel(const float* __restrict__ tf,
    const float* __restrict__ kw, const float* __restrict__ kb,
    const float* __restrict__ vw, const float* __restrict__ vb,
    const float* __restrict__ lsp,
    h16* __restrict__ ko, h16* __restrict__ vo, float* __restrict__ padf)
{
  __shared__ h16 st[4 * 512];
  __shared__ float kro[4 * 256];
  __shared__ float ssc[4];
  int bx = blockIdx.x, b = bx / 20, tg = bx % 20, t0 = tg * 4;
  int tid = threadIdx.x, lane = tid & 63, wid = tid >> 6;
  for (int i = tid; i < 4 * 512; i += 256) {
    int tl = i >> 9, j = i & 511, t = t0 + tl;
    float v = (t < 77) ? tf[((size_t)b * 77 + t) * 512 + j] : 0.f;
    st[i] = (h16)v;
  }
  __syncthreads();
  {
    int t = t0 + wid;
    float a = 0.f;
    #pragma unroll
    for (int j = 0; j < 8; j++) a += fabsf((float)st[wid * 512 + lane + j * 64]);
    #pragma unroll
    for (int o = 32; o; o >>= 1) a += __shfl_xor(a, o);
    if (lane == 0) padf[b * 80 + t] = (a <= 1e-6f) ? -1e30f : 0.f;
  }
  int c = tid;
  float kacc[4], vacc[4];
  #pragma unroll
  for (int tl = 0; tl < 4; tl++) { kacc[tl] = kb[c]; vacc[tl] = vb[c]; }
  for (int j = 0; j < 512; j++) {
    float wkv = kw[(size_t)j * 256 + c];
    float wvv = vw[(size_t)j * 256 + c];
    #pragma unroll
    for (int tl = 0; tl < 4; tl++) {
      float x = (float)st[tl * 512 + j];
      kacc[tl] += x * wkv; vacc[tl] += x * wvv;
    }
  }
  #pragma unroll
  for (int tl = 0; tl < 4; tl++) kro[tl * 256 + c] = kacc[tl] * kacc[tl];
  __syncthreads();
  {
    float s2 = kro[wid * 256 + lane] + kro[wid * 256 + lane + 64]
             + kro[wid * 256 + lane + 128] + kro[wid * 256 + lane + 192];
    #pragma unroll
    for (int o = 32; o; o >>= 1) s2 += __shfl_xor(s2, o);
    if (lane == 0) {
      float ls = lsp[0];
      float scale = __expf(fminf(fmaxf(ls, -2.f), 2.f)) * rsqrtf(32.f);
      ssc[wid] = scale / fmaxf(sqrtf(s2), 1e-6f);
    }
  }
  __syncthreads();
  int h = c >> 5, d = c & 31, g = d >> 3, e = d & 7;
  #pragma unroll
  for (int tl = 0; tl < 4; tl++) {
    int t = t0 + tl;
    int kt = t >> 4, l15 = t & 15, ln = g * 16 + l15;
    size_t koff = ((((size_t)(b * 8 + h) * 5 + kt) * 64) + ln) * 8 + e;
    size_t voff = (((size_t)(b * 8 + h) * 80) + t) * 32 + d;
    ko[koff] = (t < 77) ? (h16)(kacc[tl] * ssc[tl]) : (h16)0.f;
    vo[voff] = (t < 77) ? (h16)vacc[tl] : (h16)0.f;
  }
}

// ---------------- LN1 + gate + fp16 x ----------------
__global__ __launch_bounds__(256) void ln1_kernel(const float* __restrict__ vis,
    const float* __restrict__ w, const float* __restrict__ bia,
    const float* __restrict__ gw, const float* __restrict__ gb,
    h16* __restrict__ x, float* __restrict__ gate)
{
  int lane = threadIdx.x & 63;
  size_t row = (size_t)blockIdx.x * 4 + (threadIdx.x >> 6);
  const float4 v = ((const float4*)(vis + row * 256))[lane];
  float s = v.x + v.y + v.z + v.w;
  float q = v.x * v.x + v.y * v.y + v.z * v.z + v.w * v.w;
  #pragma unroll
  for (int o = 32; o; o >>= 1) { s += __shfl_xor(s, o); q += __shfl_xor(q, o); }
  float mean = s * (1.f / 256.f);
  float rstd = rsqrtf(q * (1.f / 256.f) - mean * mean + 1e-5f);
  float4 wv = ((const float4*)w)[lane], bv = ((const float4*)bia)[lane];
  float x0 = (v.x - mean) * rstd * wv.x + bv.x;
  float x1 = (v.y - mean) * rstd * wv.y + bv.y;
  float x2 = (v.z - mean) * rstd * wv.z + bv.z;
  float x3 = (v.w - mean) * rstd * wv.w + bv.w;
  float4 gv = ((const float4*)gw)[lane];
  float g = x0 * gv.x + x1 * gv.y + x2 * gv.z + x3 * gv.w;
  #pragma unroll
  for (int o = 32; o; o >>= 1) g += __shfl_xor(g, o);
  if (lane == 0) gate[row] = 1.f / (1.f + __expf(-(g + gb[0])));
  halfx4 o4; o4[0] = (h16)x0; o4[1] = (h16)x1; o4[2] = (h16)x2; o4[3] = (h16)x3;
  ((halfx4*)(x + row * 256))[lane] = o4;
}

// ---------------- gemmQ: q = l2norm(x @ qwT^T + qb), tile 64x256, T2-swizzled LDS ----------------
__global__ __launch_bounds__(256) void gemmQ_kernel(const h16* __restrict__ A,
    const h16* __restrict__ Wt, const float* __restrict__ bias, h16* __restrict__ outp)
{
  __shared__ char sA[8192];
  __shared__ char sB[32768];
  int m0 = blockIdx.x * 64;
  int tid = threadIdx.x, lane = tid & 63, wid = tid >> 6;
  int wn = wid;
  int l15 = lane & 15, l4 = lane >> 4, xk = l15 & 7;
  f32x4 acc[4][4];
  #pragma unroll
  for (int a = 0; a < 4; a++)
    #pragma unroll
    for (int b2 = 0; b2 < 4; b2++) acc[a][b2] = (f32x4){0.f, 0.f, 0.f, 0.f};
  const size_t sa = 512;
  int srow = lane >> 3;
  int scol = ((lane & 7) ^ srow) * 16;
  const char* Ab = (const char*)A + (size_t)m0 * sa + scol;
  const char* Bb = (const char*)Wt + scol;
  for (int k0 = 0; k0 < 256; k0 += 64) {
    #pragma unroll
    for (int cc = 0; cc < 2; cc++) {
      int ch = wid * 2 + cc;
      gload_lds16(Ab + (size_t)(ch * 8 + srow) * sa + k0 * 2, sA + ch * 1024);
    }
    #pragma unroll
    for (int cc = 0; cc < 8; cc++) {
      int ch = wid * 8 + cc;
      gload_lds16(Bb + (size_t)(ch * 8 + srow) * sa + k0 * 2, sB + ch * 1024);
    }
    asm volatile("s_waitcnt vmcnt(0)" ::: "memory");
    __syncthreads();
    #pragma unroll
    for (int ks = 0; ks < 2; ks++) {
      halfx8 af[4], bf[4];
      #pragma unroll
      for (int f = 0; f < 4; f++) {
        af[f] = *(const halfx8*)(sA + (f * 16 + l15) * 128 + (((ks * 4 + l4) ^ xk) * 16));
        bf[f] = *(const halfx8*)(sB + (wn * 64 + f * 16 + l15) * 128 + (((ks * 4 + l4) ^ xk) * 16));
      }
      #pragma unroll
      for (int fm = 0; fm < 4; fm++)
        #pragma unroll
        for (int fn = 0; fn < 4; fn++)
          acc[fm][fn] = __builtin_amdgcn_mfma_f32_16x16x32_f16(af[fm], bf[fn], acc[fm][fn], 0, 0, 0);
    }
    __syncthreads();
  }
  float bv[4];
  #pragma unroll
  for (int fn = 0; fn < 4; fn++) bv[fn] = bias[wn * 64 + fn * 16 + l15];
  float ps[4][4];
  #pragma unroll
  for (int fm = 0; fm < 4; fm++)
    #pragma unroll
    for (int r = 0; r < 4; r++) {
      float s = 0.f;
      #pragma unroll
      for (int fn = 0; fn < 4; fn++) {
        float v = acc[fm][fn][r] + bv[fn];
        acc[fm][fn][r] = v;
        s += v * v;
      }
      ps[fm][r] = s;
    }
  #pragma unroll
  for (int o = 1; o <= 8; o <<= 1)
    #pragma unroll
    for (int fm = 0; fm < 4; fm++)
      #pragma unroll
      for (int r = 0; r < 4; r++) ps[fm][r] += __shfl_xor(ps[fm][r], o);
  if (l15 == 0) {
    #pragma unroll
    for (int fm = 0; fm < 4; fm++)
      #pragma unroll
      for (int r = 0; r < 4; r++)
        ((float*)sA)[(fm * 16 + l4 * 4 + r) * 4 + wn] = ps[fm][r];
  }
  __syncthreads();
  #pragma unroll
  for (int fm = 0; fm < 4; fm++)
    #pragma unroll
    for (int r = 0; r < 4; r++) {
      const float* p = (const float*)sA + (fm * 16 + l4 * 4 + r) * 4;
      float S = p[0] + p[1] + p[2] + p[3];
      float sc = 1.f / fmaxf(sqrtf(S), 1e-6f);
      size_t row = (size_t)(m0 + fm * 16 + l4 * 4 + r);
      #pragma unroll
      for (int fn = 0; fn < 4; fn++)
        outp[row * 256 + wn * 64 + fn * 16 + l15] = (h16)(acc[fm][fn][r] * sc);
    }
}

// ---------------- gemmO: y2 = LN2(x + alpha*gate*(aligned @ owT^T + ob)), T2-swizzled ----------------
__global__ __launch_bounds__(256) void gemmO_kernel(const h16* __restrict__ A,
    const h16* __restrict__ Wt, const float* __restrict__ ob,
    const h16* __restrict__ x, const float* __restrict__ gate,
    const float* __restrict__ alphap, const float* __restrict__ w2,
    const float* __restrict__ b2, h16* __restrict__ outp)
{
  __shared__ char sA[8192];
  __shared__ char sB[32768];
  int m0 = blockIdx.x * 64;
  int tid = threadIdx.x, lane = tid & 63, wid = tid >> 6;
  int wn = wid;
  int l15 = lane & 15, l4 = lane >> 4, xk = l15 & 7;
  f32x4 acc[4][4];
  #pragma unroll
  for (int a = 0; a < 4; a++)
    #pragma unroll
    for (int b2_ = 0; b2_ < 4; b2_++) acc[a][b2_] = (f32x4){0.f, 0.f, 0.f, 0.f};
  const size_t sa = 512;
  int srow = lane >> 3;
  int scol = ((lane & 7) ^ srow) * 16;
  const char* Ab = (const char*)A + (size_t)m0 * sa + scol;
  const char* Bb = (const char*)Wt + scol;
  for (int k0 = 0; k0 < 256; k0 += 64) {
    #pragma unroll
    for (int cc = 0; cc < 2; cc++) {
      int ch = wid * 2 + cc;
      gload_lds16(Ab + (size_t)(ch * 8 + srow) * sa + k0 * 2, sA + ch * 1024);
    }
    #pragma unroll
    for (int cc = 0; cc < 8; cc++) {
      int ch = wid * 8 + cc;
      gload_lds16(Bb + (size_t)(ch * 8 + srow) * sa + k0 * 2, sB + ch * 1024);
    }
    asm volatile("s_waitcnt vmcnt(0)" ::: "memory");
    __syncthreads();
    #pragma unroll
    for (int ks = 0; ks < 2; ks++) {
      halfx8 af[4], bf[4];
      #pragma unroll
      for (int f = 0; f < 4; f++) {
        af[f] = *(const halfx8*)(sA + (f * 16 + l15) * 128 + (((ks * 4 + l4) ^ xk) * 16));
        bf[f] = *(const halfx8*)(sB + (wn * 64 + f * 16 + l15) * 128 + (((ks * 4 + l4) ^ xk) * 16));
      }
      #pragma unroll
      for (int fm = 0; fm < 4; fm++)
        #pragma unroll
        for (int fn = 0; fn < 4; fn++)
          acc[fm][fn] = __builtin_amdgcn_mfma_f32_16x16x32_f16(af[fm], bf[fn], acc[fm][fn], 0, 0, 0);
    }
    __syncthreads();
  }
  float bv[4], w2v[4], b2v[4];
  #pragma unroll
  for (int fn = 0; fn < 4; fn++) {
    int col = wn * 64 + fn * 16 + l15;
    bv[fn] = ob[col]; w2v[fn] = w2[col]; b2v[fn] = b2[col];
  }
  float al = alphap[0];
  float s1[4][4], s2[4][4];
  #pragma unroll
  for (int fm = 0; fm < 4; fm++)
    #pragma unroll
    for (int r = 0; r < 4; r++) {
      size_t row = (size_t)(m0 + fm * 16 + l4 * 4 + r);
      float ga = al * gate[row];
      float a1 = 0.f, a2 = 0.f;
      #pragma unroll
      for (int fn = 0; fn < 4; fn++) {
        float v = acc[fm][fn][r] + bv[fn];
        float xv = (float)x[row * 256 + wn * 64 + fn * 16 + l15];
        float y = xv + ga * v;
        acc[fm][fn][r] = y;
        a1 += y; a2 += y * y;
      }
      s1[fm][r] = a1; s2[fm][r] = a2;
    }
  #pragma unroll
  for (int o = 1; o <= 8; o <<= 1)
    #pragma unroll
    for (int fm = 0; fm < 4; fm++)
      #pragma unroll
      for (int r = 0; r < 4; r++) {
        s1[fm][r] += __shfl_xor(s1[fm][r], o);
        s2[fm][r] += __shfl_xor(s2[fm][r], o);
      }
  if (l15 == 0) {
    #pragma unroll
    for (int fm = 0; fm < 4; fm++)
      #pragma unroll
      for (int r = 0; r < 4; r++) {
        int rr = fm * 16 + l4 * 4 + r;
        ((float*)sA)[rr * 8 + wn * 2 + 0] = s1[fm][r];
        ((float*)sA)[rr * 8 + wn * 2 + 1] = s2[fm][r];
      }
  }
  __syncthreads();
  #pragma unroll
  for (int fm = 0; fm < 4; fm++)
    #pragma unroll
    for (int r = 0; r < 4; r++) {
      int rr = fm * 16 + l4 * 4 + r;
      const float* p = (const float*)sA + rr * 8;
      float S1 = p[0] + p[2] + p[4] + p[6];
      float S2 = p[1] + p[3] + p[5] + p[7];
      float mean = S1 * (1.f / 256.f);
      float var = S2 * (1.f / 256.f) - mean * mean;
      float rstd = rsqrtf(var + 1e-5f);
      size_t row = (size_t)(m0 + rr);
      #pragma unroll
      for (int fn = 0; fn < 4; fn++) {
        float y = acc[fm][fn][r];
        outp[row * 256 + wn * 64 + fn * 16 + l15] =
            (h16)((y - mean) * rstd * w2v[fn] + b2v[fn]);
      }
    }
}

// ---------------- fused FFN v4: chunk=64, 1 barrier/chunk, gemm2 pipelined 1 chunk behind ----
// 512 threads = 8 waves. Block owns 128 rows. 16 hidden chunks of 64.
// Window c: stage W1(c+1)->sW1[(c+1)&1], stage W2(c)->sW2[c&1], gemm1(c) from sW1[c&1],
// gelu(c)->sH[c&1], gemm2(c-1) from sH/sW2[(c-1)&1]. All buffers disjoint per window.
// gelu(c) (VALU) and gemm2(c-1) (MFMA) are independent -> scheduler interleaves; waves
// drift freely in one barrier-free region per chunk. b1 prefetched in registers.
// LDS = 2x32K (W1) + 2x32K (W2) + 2x16K (H) = 163840 B (full pool, 1 block/CU).
__device__ __forceinline__ void ffn_stage_w1(const h16* __restrict__ w1t,
                                             int c, char* dW1, int tid, int wid)
{
  #pragma unroll
  for (int j = 0; j < 4; j++) {
    int i = j * 512 + tid;
    int r = i >> 5, g = i & 31;
    gload_lds16(w1t + (size_t)(c * 64 + r) * 256 + ((g ^ (r & 7)) * 8),
                dW1 + (j * 512 + wid * 64) * 16);
  }
}
__device__ __forceinline__ void ffn_stage_w2(const h16* __restrict__ w2t,
                                             int c, char* dW2, int tid, int wid)
{
  #pragma unroll
  for (int j = 0; j < 4; j++) {
    int i = j * 512 + tid;
    int r = i >> 3, g = i & 7;
    gload_lds16(w2t + (size_t)r * 1024 + c * 64 + ((g ^ (r & 7)) * 8),
                dW2 + (j * 512 + wid * 64) * 16);
  }
}

__global__ __launch_bounds__(512, 2) void ffn_fused_kernel(
    const h16* __restrict__ y2g, const h16* __restrict__ w1t, const float* __restrict__ b1,
    const h16* __restrict__ w2t, const float* __restrict__ b2, float* __restrict__ outp)
{
  // [0,65536)        sW1[2]  [64 n1][256 k] h16, XOR-swizzled granules
  // [65536,131072)   sW2[2]  [256 n][64 k] h16, XOR-swizzled granules
  // [131072,163840)  sH[2]   [128][64] h16, XOR-swizzled granules
  __shared__ char smem[163840];
  float* sE = (float*)smem;     // [64][264] f32 epilogue (aliases sW1 + sW2[0] head)

  int m0 = blockIdx.x * 128;
  int tid = threadIdx.x, lane = tid & 63, wid = tid >> 6;
  int l15 = lane & 15, l4 = lane >> 4;
  int wm1 = wid >> 1, wn1 = wid & 1;
  int wm2 = wid >> 2, wn2 = wid & 3;

  // cache y2 A-fragments in registers (reused by all 16 chunks)
  halfx8 afy[2][8];
  #pragma unroll
  for (int fm = 0; fm < 2; fm++) {
    size_t row = (size_t)(m0 + wm1 * 32 + fm * 16 + l15);
    #pragma unroll
    for (int ks = 0; ks < 8; ks++)
      afy[fm][ks] = *(const halfx8*)&y2g[row * 256 + ks * 32 + l4 * 8];
  }

  f32x4 acc2[4][4];
  #pragma unroll
  for (int a = 0; a < 4; a++)
    #pragma unroll
    for (int b_ = 0; b_ < 4; b_++) acc2[a][b_] = (f32x4){0.f, 0.f, 0.f, 0.f};

  // prologue: stage W1(0) into buffer 0; b1(0) into regs
  ffn_stage_w1(w1t, 0, smem, tid, wid);
  float b1v0 = b1[wn1 * 32 + l15];
  float b1v1 = b1[wn1 * 32 + 16 + l15];
  asm volatile("s_waitcnt vmcnt(0)" ::: "memory");
  __builtin_amdgcn_s_barrier();
  asm volatile("" ::: "memory");

  for (int c = 0; c < 16; c++) {
    int buf = c & 1;
    char* sW1c = smem + buf * 32768;
    // issue next-chunk W1 and this-chunk W2 DMA at window top (latency hides under compute)
    if (c < 15) ffn_stage_w1(w1t, c + 1, smem + (buf ^ 1) * 32768, tid, wid);
    ffn_stage_w2(w2t, c, smem + 65536 + buf * 32768, tid, wid);
    float nb0 = 0.f, nb1 = 0.f;
    if (c < 15) {
      nb0 = b1[(c + 1) * 64 + wn1 * 32 + l15];
      nb1 = b1[(c + 1) * 64 + wn1 * 32 + 16 + l15];
    }

    // gemm1(c): H_chunk[128][64] tile 32x32 per wave
    f32x4 a1[2][2];
    #pragma unroll
    for (int a = 0; a < 2; a++)
      #pragma unroll
      for (int b_ = 0; b_ < 2; b_++) a1[a][b_] = (f32x4){0.f, 0.f, 0.f, 0.f};
    __builtin_amdgcn_s_setprio(1);
    #pragma unroll
    for (int ks = 0; ks < 8; ks++) {
      #pragma unroll
      for (int fc = 0; fc < 2; fc++) {
        int nrow = wn1 * 32 + fc * 16 + l15;
        halfx8 bf = *(const halfx8*)(sW1c + (size_t)nrow * 512 + (((ks * 4 + l4) ^ (nrow & 7)) * 16));
        #pragma unroll
        for (int fm = 0; fm < 2; fm++)
          a1[fm][fc] = __builtin_amdgcn_mfma_f32_16x16x32_f16(afy[fm][ks], bf, a1[fm][fc], 0, 0, 0);
      }
    }
    __builtin_amdgcn_s_setprio(0);

    // gelu(c) -> sH[buf]
    {
      char* sHc = smem + 131072 + buf * 16384;
      #pragma unroll
      for (int fm = 0; fm < 2; fm++)
        #pragma unroll
        for (int fc = 0; fc < 2; fc++)
          #pragma unroll
          for (int r = 0; r < 4; r++) {
            int row = wm1 * 32 + fm * 16 + l4 * 4 + r;
            int col = wn1 * 32 + fc * 16 + l15;
            float v = fast_gelu(a1[fm][fc][r] + (fc ? b1v1 : b1v0));
            ((h16*)(sHc + row * 128 + (((col >> 3) ^ (row & 7)) * 16)))[col & 7] = (h16)v;
          }
    }

    // gemm2(c-1): acc2 += H(c-1) @ W2(c-1)  — independent of gelu(c), interleaves with it
    if (c > 0) {
      char* sHp = smem + 131072 + (buf ^ 1) * 16384;
      char* sW2p = smem + 65536 + (buf ^ 1) * 32768;
      __builtin_amdgcn_s_setprio(1);
      #pragma unroll
      for (int ks = 0; ks < 2; ks++) {
        halfx8 ah[4], bw[4];
        #pragma unroll
        for (int f = 0; f < 4; f++) {
          int hrow = wm2 * 64 + f * 16 + l15;
          ah[f] = *(const halfx8*)(sHp + hrow * 128 + (((ks * 4 + l4) ^ (hrow & 7)) * 16));
          int wrow = wn2 * 64 + f * 16 + l15;
          bw[f] = *(const halfx8*)(sW2p + (size_t)wrow * 128 + (((ks * 4 + l4) ^ (wrow & 7)) * 16));
        }
        #pragma unroll
        for (int fm = 0; fm < 4; fm++)
          #pragma unroll
          for (int fn = 0; fn < 4; fn++)
            acc2[fm][fn] = __builtin_amdgcn_mfma_f32_16x16x32_f16(ah[fm], bw[fn], acc2[fm][fn], 0, 0, 0);
      }
      __builtin_amdgcn_s_setprio(0);
    }

    // single barrier per chunk: sH writes drained (lgkm), W1(c+1)/W2(c) DMA landed (vm)
    asm volatile("s_waitcnt lgkmcnt(0)" ::: "memory");
    asm volatile("s_waitcnt vmcnt(0)" ::: "memory");
    __builtin_amdgcn_s_barrier();
    asm volatile("" ::: "memory");
    b1v0 = nb0; b1v1 = nb1;
  }

  // final gemm2(15): sH[1], sW2[1]
  {
    char* sHp = smem + 131072 + 16384;
    char* sW2p = smem + 65536 + 32768;
    __builtin_amdgcn_s_setprio(1);
    #pragma unroll
    for (int ks = 0; ks < 2; ks++) {
      halfx8 ah[4], bw[4];
      #pragma unroll
      for (int f = 0; f < 4; f++) {
        int hrow = wm2 * 64 + f * 16 + l15;
        ah[f] = *(const halfx8*)(sHp + hrow * 128 + (((ks * 4 + l4) ^ (hrow & 7)) * 16));
        int wrow = wn2 * 64 + f * 16 + l15;
        bw[f] = *(const halfx8*)(sW2p + (size_t)wrow * 128 + (((ks * 4 + l4) ^ (wrow & 7)) * 16));
      }
      #pragma unroll
      for (int fm = 0; fm < 4; fm++)
        #pragma unroll
        for (int fn = 0; fn < 4; fn++)
          acc2[fm][fn] = __builtin_amdgcn_mfma_f32_16x16x32_f16(ah[fm], bw[fn], acc2[fm][fn], 0, 0, 0);
    }
    __builtin_amdgcn_s_setprio(0);
  }

  // epilogue: two half-passes via padded f32 LDS; coalesced float4 stores + residual + b2
  // sE (0..67584) is disjoint from final-gemm2's reads (sW2[1] at 98304+, sH[1] at 147456+)
  int rowl = tid >> 3, cg = tid & 7;
  #pragma unroll
  for (int half = 0; half < 2; half++) {
    if (wm2 == half) {
      #pragma unroll
      for (int fm = 0; fm < 4; fm++)
        #pragma unroll
        for (int fn = 0; fn < 4; fn++)
          #pragma unroll
          for (int r = 0; r < 4; r++)
            sE[(fm * 16 + l4 * 4 + r) * 264 + wn2 * 64 + fn * 16 + l15] = acc2[fm][fn][r];
    }
    __syncthreads();
    size_t grow = (size_t)(m0 + half * 64 + rowl);
    #pragma unroll
    for (int k = 0; k < 8; k++) {
      int c0 = cg * 4 + k * 32;
      float4 v = *(float4*)&sE[rowl * 264 + c0];
      halfx4 rv = *(const halfx4*)&y2g[grow * 256 + c0];
      float4 bb = *(const float4*)&b2[c0];
      float4 o;
      o.x = v.x + (float)rv[0] + bb.x;
      o.y = v.y + (float)rv[1] + bb.y;
      o.z = v.z + (float)rv[2] + bb.z;
      o.w = v.w + (float)rv[3] + bb.w;
      *(float4*)&outp[grow * 256 + c0] = o;
    }
    __syncthreads();
  }
}

// ---------------- attention v6: coalesced fragment-order K, compact V ----------------
__global__ __launch_bounds__(256) void attn_kernel(const h16* __restrict__ q,
    const h16* __restrict__ kk,   // kT[b][h][kt][lane][8]
    const h16* __restrict__ vv,   // vT[b][h][80][32]
    const float* __restrict__ padf,
    h16* __restrict__ outp)       // aliases q (in-place per slice)
{
  int bx = blockIdx.x;
  int wid = threadIdx.x >> 6, lane = threadIdx.x & 63;
  int l15 = lane & 15, g = lane >> 4;
  int b = bx >> 8;
  size_t qrow = (size_t)bx * 64 + wid * 16 + l15;
  int base4 = g * 4;
  float pad4[5][4];
  #pragma unroll
  for (int kt = 0; kt < 5; kt++) {
    float4 p4 = *(const float4*)&padf[b * 80 + kt * 16 + base4];
    pad4[kt][0] = p4.x; pad4[kt][1] = p4.y; pad4[kt][2] = p4.z; pad4[kt][3] = p4.w;
  }
  const h16* qp = &q[qrow * 256 + g * 8];
  h16* op = &outp[qrow * 256 + g * 8];
  #pragma unroll 2
  for (int h = 0; h < 8; h++) {
    int ho = h * 32;
    halfx8 qf = *(const halfx8*)(qp + ho);
    const h16* kph = kk + (((size_t)(b * 8 + h) * 5) * 64 + lane) * 8;
    const h16* vph = vv + ((size_t)(b * 8 + h) * 80) * 32 + g * 8;
    f32x4 acc[5];
    #pragma unroll
    for (int kt = 0; kt < 5; kt++) {
      halfx8 kf = *(const halfx8*)(kph + kt * 512);
      acc[kt] = __builtin_amdgcn_mfma_f32_16x16x32_f16(kf, qf, (f32x4){0.f, 0.f, 0.f, 0.f}, 0, 0, 0);
    }
    unsigned pv0 = 0u, pv1 = 0u, pv2 = 0u, pv3 = 0u, pv4 = 0u;
    #pragma unroll
    for (int kt = 0; kt < 5; kt++) {
      #pragma unroll
      for (int r = 0; r < 4; r++) {
        float s = acc[kt][r] + pad4[kt][r];
        int bi = __float_as_int(s);
        unsigned u = ((unsigned)(bi ^ ((bi >> 31) | (int)0x80000000)) & 0xFFFFFF80u)
                   | (unsigned)(base4 + kt * 16 + r);
        unsigned a;
        a = umax_(pv0, u); u = umin_(pv0, u); pv0 = a;
        a = umax_(pv1, u); u = umin_(pv1, u); pv1 = a;
        a = umax_(pv2, u); u = umin_(pv2, u); pv2 = a;
        a = umax_(pv3, u); u = umin_(pv3, u); pv3 = a;
        pv4 = umax_(pv4, u);
      }
    }
    #pragma unroll
    for (int mrd = 0; mrd < 2; mrd++) {
      int msk = mrd ? 32 : 16;
      unsigned b0 = (unsigned)__shfl_xor((int)pv0, msk);
      unsigned b1 = (unsigned)__shfl_xor((int)pv1, msk);
      unsigned b2 = (unsigned)__shfl_xor((int)pv2, msk);
      unsigned b3 = (unsigned)__shfl_xor((int)pv3, msk);
      unsigned b4 = (unsigned)__shfl_xor((int)pv4, msk);
      unsigned c0 = umax_(pv0, b0);
      unsigned c1 = umax_(umax_(umin_(pv0, b0), pv1), b1);
      unsigned c2 = umax_(umax_(umin_(pv0, b1), umin_(pv1, b0)), umax_(pv2, b2));
      unsigned c3 = umax_(umax_(umax_(umin_(pv0, b2), umin_(pv1, b1)), umin_(pv2, b0)), umax_(pv3, b3));
      unsigned c4 = umax_(umax_(umax_(umin_(pv0, b3), umin_(pv1, b2)),
                                umax_(umin_(pv2, b1), umin_(pv3, b0))), umax_(pv4, b4));
      pv0 = c0; pv1 = c1; pv2 = c2; pv3 = c3; pv4 = c4;
    }
    unsigned pvs[5] = {pv0, pv1, pv2, pv3, pv4};
    float pw[5]; int ti[5]; float den = 0.f;
    #pragma unroll
    for (int k = 0; k < 5; k++) {
      unsigned u = pvs[k];
      int sg = ((int)u) >> 31;
      float tv = __int_as_float(u ^ (0x80000000u | (unsigned)~sg));
      ti[k] = (int)(u & 0x7Fu);
      pw[k] = __expf(tv);
      den += pw[k];
    }
    float inv = 1.f / den;
    halfx8 o8 = {};
    #pragma unroll
    for (int k = 0; k < 5; k++) {
      h16 ph = (h16)(pw[k] * inv);
      halfx8 v = *(const halfx8*)(vph + ti[k] * 32);
      halfx8 p8 = {ph, ph, ph, ph, ph, ph, ph, ph};
      o8 = o8 + p8 * v;
    }
    *(halfx8*)(op + ho) = o8;
  }
}

extern "C" void kernel_launch(void* const* d_in, const int* in_sizes, int n_in,
                              void* d_out, int out_size, void* d_ws, size_t ws_size,
                              hipStream_t stream)
{
  const float* vis = (const float*)d_in[0];
  const float* tf  = (const float*)d_in[1];
  const float* n1w = (const float*)d_in[2];
  const float* n1b = (const float*)d_in[3];
  const float* qw  = (const float*)d_in[4];
  const float* qb  = (const float*)d_in[5];
  const float* kw  = (const float*)d_in[6];
  const float* kb  = (const float*)d_in[7];
  const float* vw  = (const float*)d_in[8];
  const float* vb  = (const float*)d_in[9];
  const float* ow  = (const float*)d_in[10];
  const float* ob  = (const float*)d_in[11];
  const float* gw  = (const float*)d_in[12];
  const float* gb  = (const float*)d_in[13];
  const float* ls  = (const float*)d_in[14];
  const float* al  = (const float*)d_in[15];
  const float* n2w = (const float*)d_in[16];
  const float* n2b = (const float*)d_in[17];
  const float* f1w = (const float*)d_in[18];
  const float* f1b = (const float*)d_in[19];
  const float* f2w = (const float*)d_in[20];
  const float* f2b = (const float*)d_in[21];

  char* ws = (char*)d_ws;
  const size_t MB_ = 1024ull * 1024ull;
  h16*  kS   = (h16*)(ws + 0 * MB_);      // kT: 320 KB
  h16*  vS   = (h16*)(ws + 1 * MB_);      // vT: 320 KB
  float* padf = (float*)(ws + 2 * MB_);   // [8][80] f32
  float* gate = (float*)(ws + 3 * MB_);   // 512 KB
  h16*  qwT  = (h16*)(ws + 4 * MB_);      // 128 KB
  h16*  owT  = (h16*)(ws + 5 * MB_);      // 128 KB
  h16*  f1T  = (h16*)(ws + 6 * MB_);      // 512 KB
  h16*  f2T  = (h16*)(ws + 7 * MB_);      // 512 KB
  h16*  xh   = (h16*)(ws + 16 * MB_);     // 64 MB: x
  h16*  qh   = (h16*)(ws + 80 * MB_);     // 64 MB: q / attn-out in place
  h16*  alg  = (h16*)(ws + 144 * MB_);    // 64 MB: y2

  conv_all_kernel<<<2560, 256, 0, stream>>>(qw, ow, f1w, f2w, qwT, owT, f1T, f2T);

  text_kv_kernel<<<160, 256, 0, stream>>>(tf, kw, kb, vw, vb, ls, kS, vS, padf);
  ln1_kernel<<<32768, 256, 0, stream>>>(vis, n1w, n1b, gw, gb, xh, gate);

  gemmQ_kernel<<<2048, 256, 0, stream>>>(xh, qwT, qb, qh);

  attn_kernel<<<2048, 256, 0, stream>>>(qh, kS, vS, padf, qh);

  gemmO_kernel<<<2048, 256, 0, stream>>>(qh, owT, ob, xh, gate, al, n2w, n2b, alg);

  // fused FFN: d_out = alg + gelu(alg@W1+b1)@W2 + b2
  ffn_fused_kernel<<<1024, 512, 0, stream>>>(alg, f1T, f1b, f2T, f2b, (float*)d_out);
}